// Round 5
// baseline (112.922 us; speedup 1.0000x reference)
//
#include <hip/hip_runtime.h>
#include <hip/hip_bf16.h>
#include <math.h>

typedef short short8 __attribute__((ext_vector_type(8)));
typedef float f32x4 __attribute__((ext_vector_type(4)));

static constexpr int N = 8192;
static constexpr int FIN = 512;
static constexpr int FOUT = 128;
static constexpr float PHI = 3.1415926f * 0.3f;
static constexpr float A_PARA = 0.5f;
static constexpr float EPS_BALL = 4e-3f;
static constexpr float L2E = 1.4426950408889634f;   // log2(e)

__device__ __forceinline__ unsigned short f2b(float f) {
    union { float f; unsigned u; } v; v.f = f;
    unsigned r = v.u + 0x7fffu + ((v.u >> 16) & 1u);
    return (unsigned short)(r >> 16);
}

// monotone f32 -> u32 key for atomicMax-based float max
__device__ __forceinline__ unsigned f2key(float x) {
    unsigned b = __float_as_uint(x);
    return (b & 0x80000000u) ? ~b : (b | 0x80000000u);
}
__device__ __forceinline__ float key2f(unsigned k) {
    unsigned b = (k & 0x80000000u) ? (k ^ 0x80000000u) : ~k;
    return __uint_as_float(b);
}

__device__ __forceinline__ short8 cvt8(float4 x0, float4 x1) {
    short8 r;
    r[0] = (short)f2b(x0.x); r[1] = (short)f2b(x0.y);
    r[2] = (short)f2b(x0.z); r[3] = (short)f2b(x0.w);
    r[4] = (short)f2b(x1.x); r[5] = (short)f2b(x1.y);
    r[6] = (short)f2b(x1.z); r[7] = (short)f2b(x1.w);
    return r;
}

// w = exp2( lrelu(s'+t') - m' ) masked by adj; everything pre-scaled by log2e.
__device__ __forceinline__ void cw(float* w, const int4 a, const float4 tv,
                                   float sA, float mA) {
    float z;
    z = sA + tv.x; w[0] = a.x > 0 ? __builtin_amdgcn_exp2f(fmaxf(z, 0.2f * z) - mA) : 0.f;
    z = sA + tv.y; w[1] = a.y > 0 ? __builtin_amdgcn_exp2f(fmaxf(z, 0.2f * z) - mA) : 0.f;
    z = sA + tv.z; w[2] = a.z > 0 ? __builtin_amdgcn_exp2f(fmaxf(z, 0.2f * z) - mA) : 0.f;
    z = sA + tv.w; w[3] = a.w > 0 ? __builtin_amdgcn_exp2f(fmaxf(z, 0.2f * z) - mA) : 0.f;
}

// Kernel 0: W f32[512][128] -> Wt bf16[128][512]; block 0 also zeroes Tkey + denb
// (folds the two hipMemsetAsync dispatches away).
__global__ __launch_bounds__(256) void k0_wt(const float* __restrict__ W,
                                             unsigned short* __restrict__ Wt,
                                             unsigned* __restrict__ Tkey,
                                             float* __restrict__ denb) {
    __shared__ float sh[32][33];
    const int t = threadIdx.x;
    const int k0 = (blockIdx.x >> 2) * 32, c0 = (blockIdx.x & 3) * 32;
    {
        int r = t >> 3, c4 = (t & 7) * 4;
        float4 v = *(const float4*)(W + (size_t)(k0 + r) * FOUT + c0 + c4);
        sh[r][c4] = v.x; sh[r][c4 + 1] = v.y; sh[r][c4 + 2] = v.z; sh[r][c4 + 3] = v.w;
    }
    __syncthreads();
    int cc = t >> 3, k4 = (t & 7) * 4;
    ushort4 o;
    o.x = f2b(sh[k4][cc]); o.y = f2b(sh[k4 + 1][cc]);
    o.z = f2b(sh[k4 + 2][cc]); o.w = f2b(sh[k4 + 3][cc]);
    *(ushort4*)(Wt + (size_t)(c0 + cc) * FIN + k0 + k4) = o;
    if (blockIdx.x == 0) {
        if (t == 0) Tkey[0] = 0u;
        for (int i = t; i < N; i += 256) denb[i] = 0.f;
    }
}

// Kernel 1: Wh = h @ W via bf16 MFMA. BM=16 rows/block, grid 512 (2 blocks/CU).
// h tile (16x512) staged to LDS ONCE (single barrier); Wt read from L2.
// Outputs whbt bf16 [FOUT][N], s'=(Wh@a1)*log2e, t'=(Wh@a2)*log2e, Tkey=max key.
__global__ __launch_bounds__(256, 2) void k1_gemm(
    const float* __restrict__ h, const unsigned short* __restrict__ Wt,
    const float* __restrict__ a, unsigned short* __restrict__ whbt,
    float* __restrict__ s_out, float* __restrict__ t_out,
    unsigned* __restrict__ Tkey)
{
    __shared__ unsigned short hsb[16][520];
    __shared__ float sred[16][4], tred[16][4];
    const int t = threadIdx.x, lane = t & 63, wc = t >> 6;
    const int i0 = blockIdx.x * 16;
    const int arow = lane & 15, g = lane >> 4;

    {   // stage h tile: thread owns row r, 32 cols at col0
        const int r = t >> 4, col0 = (t & 15) * 32;
        const float* hp = h + (size_t)(i0 + r) * FIN + col0;
        #pragma unroll
        for (int u = 0; u < 4; ++u) {
            float4 x0 = *(const float4*)(hp + u * 8);
            float4 x1 = *(const float4*)(hp + u * 8 + 4);
            *(short8*)&hsb[r][col0 + u * 8] = cvt8(x0, x1);
        }
    }
    __syncthreads();

    f32x4 acc[2];
    const f32x4 zz = {0.f, 0.f, 0.f, 0.f};
    acc[0] = zz; acc[1] = zz;
    const int col_0 = wc * 32 + arow;        // cf=0 column
    const int col_1 = wc * 32 + 16 + arow;   // cf=1 column
    const unsigned short* bp0 = Wt + (size_t)col_0 * FIN + g * 8;
    const unsigned short* bp1 = Wt + (size_t)col_1 * FIN + g * 8;

    #pragma unroll
    for (int ks = 0; ks < 16; ++ks) {
        short8 af = *(const short8*)&hsb[arow][ks * 32 + g * 8];
        short8 b0 = *(const short8*)(bp0 + ks * 32);
        short8 b1 = *(const short8*)(bp1 + ks * 32);
        acc[0] = __builtin_amdgcn_mfma_f32_16x16x32_bf16(af, b0, acc[0], 0, 0, 0);
        acc[1] = __builtin_amdgcn_mfma_f32_16x16x32_bf16(af, b1, acc[1], 0, 0, 0);
    }

    const float a10 = a[col_0], a11 = a[col_1];
    const float a20 = a[FOUT + col_0], a21 = a[FOUT + col_1];
    {   // whbt store: 4 consecutive rows per (thread, cf)
        ushort4 o;
        o.x = f2b(acc[0][0]); o.y = f2b(acc[0][1]);
        o.z = f2b(acc[0][2]); o.w = f2b(acc[0][3]);
        *(ushort4*)(whbt + (size_t)col_0 * N + i0 + g * 4) = o;
        o.x = f2b(acc[1][0]); o.y = f2b(acc[1][1]);
        o.z = f2b(acc[1][2]); o.w = f2b(acc[1][3]);
        *(ushort4*)(whbt + (size_t)col_1 * N + i0 + g * 4) = o;
    }
    #pragma unroll
    for (int q = 0; q < 4; ++q) {
        float sp = acc[0][q] * a10 + acc[1][q] * a11;
        float tp = acc[0][q] * a20 + acc[1][q] * a21;
        #pragma unroll
        for (int m = 1; m < 16; m <<= 1) {
            sp += __shfl_xor(sp, m, 16);
            tp += __shfl_xor(tp, m, 16);
        }
        if (arow == 0) { sred[g * 4 + q][wc] = sp; tred[g * 4 + q][wc] = tp; }
    }
    __syncthreads();
    if (t < 16) {
        float sp = (sred[t][0] + sred[t][1] + sred[t][2] + sred[t][3]) * L2E;
        float tp = (tred[t][0] + tred[t][1] + tred[t][2] + tred[t][3]) * L2E;
        s_out[i0 + t] = sp;
        t_out[i0 + t] = tp;
        float m = tp;
        #pragma unroll
        for (int d = 1; d < 16; d <<= 1) m = fmaxf(m, __shfl_xor(m, d, 16));
        if (t == 0) atomicMax(Tkey, f2key(m));
    }
}

// Kernel 3: fused masked-softmax attention + PV (bf16 MFMA).
// Grid 512 = 64 i-tiles (BM=128) x 8 j-chunks (BJ=1024), jc = blockIdx%8 (XCD-pinned).
// Per iter issue order: whbt-next FIRST, adj(jt+2) LAST -> the pre-ds_write wait is
// a counted vmcnt(4) and the 2-deep adj prefetch (~2 iters ~1500cy cover > 900cy
// HBM latency) rides through the barrier. w computed directly in A-fragment layout.
__global__ __launch_bounds__(512, 4) void k3_attn(
    const int* __restrict__ adj, const unsigned short* __restrict__ whbt,
    const float* __restrict__ s_in, const float* __restrict__ t_in,
    const unsigned* __restrict__ Tkey,
    unsigned short* __restrict__ num_bf, float* __restrict__ num_f32,
    float* __restrict__ den_out, int slice_mode)
{
    __shared__ unsigned short bt[2][128][72];
    __shared__ float tl[1024];
    const int t = threadIdx.x, lane = t & 63, wave = t >> 6;
    const int jc = blockIdx.x & 7, it = blockIdx.x >> 3;
    const int i0 = it * 128, jbase = jc * 1024;

    tl[t] = t_in[jbase + t];
    tl[t + 512] = t_in[jbase + t + 512];

    const int arow = lane & 15, g = lane >> 4;
    const int grow = i0 + wave * 16 + arow;
    const float sA = s_in[grow];
    const float Tv = key2f(Tkey[0]);
    const float zT = sA + Tv;
    const float mA = fmaxf(zT, 0.2f * zT);
    const int* adjrow = adj + (size_t)grow * N;
    const int srow = t >> 2, scol = (t & 3) * 16;
    const unsigned short* sbase = whbt + (size_t)srow * N + jbase + scol;

    f32x4 acc[8];
    const f32x4 zz = {0.f, 0.f, 0.f, 0.f};
    #pragma unroll
    for (int c = 0; c < 8; ++c) acc[c] = zz;
    float den = 0.f;

    // prologue: stage bt tile 0; adj prefetch 2 deep (jt=0 and jt=1)
    short8 sr0 = *(const short8*)sbase;
    short8 sr1 = *(const short8*)(sbase + 8);
    int4 av0 = *(const int4*)(adjrow + jbase + g * 8);
    int4 av1 = *(const int4*)(adjrow + jbase + g * 8 + 4);
    int4 av2 = *(const int4*)(adjrow + jbase + 32 + g * 8);
    int4 av3 = *(const int4*)(adjrow + jbase + 32 + g * 8 + 4);
    int4 bv0 = *(const int4*)(adjrow + jbase + 64 + g * 8);
    int4 bv1 = *(const int4*)(adjrow + jbase + 64 + g * 8 + 4);
    int4 bv2 = *(const int4*)(adjrow + jbase + 96 + g * 8);
    int4 bv3 = *(const int4*)(adjrow + jbase + 96 + g * 8 + 4);
    *(short8*)&bt[0][srow][scol]     = sr0;
    *(short8*)&bt[0][srow][scol + 8] = sr1;
    __syncthreads();

    #pragma unroll 1
    for (int jt = 0; jt < 16; ++jt) {
        const int cur = jt & 1, jl = jt * 64;
        // whbt-next FIRST (drained at the ds_write below with a counted vmcnt)
        short8 n0, n1;
        if (jt < 15) {
            const unsigned short* p = sbase + (jt + 1) * 64;
            n0 = *(const short8*)p;
            n1 = *(const short8*)(p + 8);
        }
        // adj for jt+2 LAST (stays in flight across the barrier)
        int4 zv0, zv1, zv2, zv3;
        if (jt < 14) {
            const int* ap = adjrow + jbase + jl + 128;
            zv0 = *(const int4*)(ap + g * 8);
            zv1 = *(const int4*)(ap + g * 8 + 4);
            zv2 = *(const int4*)(ap + 32 + g * 8);
            zv3 = *(const int4*)(ap + 32 + g * 8 + 4);
        }
        // t' from LDS (lgkm only)
        float4 ta = *(const float4*)&tl[jl + g * 8];
        float4 tb = *(const float4*)&tl[jl + g * 8 + 4];
        float4 tc = *(const float4*)&tl[jl + 32 + g * 8];
        float4 td = *(const float4*)&tl[jl + 32 + g * 8 + 4];
        // phase A: 16 w's straight into A-fragments (adj already in regs)
        float w[16];
        cw(&w[0],  av0, ta, sA, mA);
        cw(&w[4],  av1, tb, sA, mA);
        cw(&w[8],  av2, tc, sA, mA);
        cw(&w[12], av3, td, sA, mA);
        #pragma unroll
        for (int e = 0; e < 16; ++e) den += w[e];
        short8 af0, af1;
        #pragma unroll
        for (int e = 0; e < 8; ++e) {
            af0[e] = (short)f2b(w[e]);
            af1[e] = (short)f2b(w[8 + e]);
        }
        // phase B: 16 MFMA, B from LDS
        #pragma unroll
        for (int c = 0; c < 8; ++c) {
            short8 bf = *(const short8*)&bt[cur][c * 16 + arow][g * 8];
            acc[c] = __builtin_amdgcn_mfma_f32_16x16x32_bf16(af0, bf, acc[c], 0, 0, 0);
        }
        #pragma unroll
        for (int c = 0; c < 8; ++c) {
            short8 bf = *(const short8*)&bt[cur][c * 16 + arow][32 + g * 8];
            acc[c] = __builtin_amdgcn_mfma_f32_16x16x32_bf16(af1, bf, acc[c], 0, 0, 0);
        }
        // stage next tile; shift adj prefetch pipeline
        if (jt < 15) {
            *(short8*)&bt[cur ^ 1][srow][scol]     = n0;
            *(short8*)&bt[cur ^ 1][srow][scol + 8] = n1;
            av0 = bv0; av1 = bv1; av2 = bv2; av3 = bv3;
            if (jt < 14) { bv0 = zv0; bv1 = zv1; bv2 = zv2; bv3 = zv3; }
            __syncthreads();
        }
    }

    // den: sum the 4 g-copies per row
    den += __shfl_xor(den, 16, 64);
    den += __shfl_xor(den, 32, 64);
    if (g == 0) atomicAdd(&den_out[grow], den);

    // num partials
    const int orow0 = i0 + wave * 16;
    if (slice_mode) {
        unsigned short* dst = num_bf + (size_t)jc * ((size_t)N * FOUT);
        #pragma unroll
        for (int c = 0; c < 8; ++c)
            #pragma unroll
            for (int q = 0; q < 4; ++q)
                dst[(size_t)(orow0 + g * 4 + q) * FOUT + c * 16 + arow] = f2b(acc[c][q]);
    } else {
        #pragma unroll
        for (int c = 0; c < 8; ++c)
            #pragma unroll
            for (int q = 0; q < 4; ++q)
                atomicAdd(&num_f32[(size_t)(orow0 + g * 4 + q) * FOUT + c * 16 + arow], acc[c][q]);
    }
}

// Kernel 4: reduce j-chunk partials, normalize, project, logmap0, elu + a*cos.
// Thread owns 8 CONTIGUOUS cols of one row -> short8 slice loads, float4 stores.
__global__ __launch_bounds__(256) void k4_epi(
    const unsigned short* __restrict__ numb, const float* __restrict__ numf,
    const float* __restrict__ den, float* __restrict__ out, int bfmode)
{
    const int row = blockIdx.x * 16 + (threadIdx.x >> 4);
    const int col0 = (threadIdx.x & 15) * 8;
    const float inv = 1.0f / den[row];
    float v[8] = {};
    if (bfmode) {
        #pragma unroll 1
        for (int s5 = 0; s5 < 8; ++s5) {
            short8 b = *(const short8*)(numb + (size_t)s5 * N * FOUT + (size_t)row * FOUT + col0);
            #pragma unroll
            for (int c = 0; c < 8; ++c)
                v[c] += __uint_as_float(((unsigned)(unsigned short)b[c]) << 16);
        }
    } else {
        #pragma unroll
        for (int c = 0; c < 8; ++c) v[c] = numf[(size_t)row * FOUT + col0 + c];
    }
    float ss = 0.f;
    #pragma unroll
    for (int c = 0; c < 8; ++c) { v[c] *= inv; ss += v[c] * v[c]; }
    #pragma unroll
    for (int m = 1; m < 16; m <<= 1) ss += __shfl_xor(ss, m, 16);
    float nrm = sqrtf(ss);
    const float maxn = 1.0f - EPS_BALL;
    float scale1 = nrm > maxn ? maxn / nrm : 1.0f;
    float pn = fminf(nrm, maxn);
    float fac;
    if (pn < 1e-6f) fac = scale1;   // artanh(x)/x -> 1
    else fac = scale1 * (0.5f * __logf((1.f + pn) / (1.f - pn))) / pn;
    float o[8];
    #pragma unroll
    for (int c = 0; c < 8; ++c) {
        float hv = v[c] * fac;
        float eluv = hv > 0.f ? hv : __expf(hv) - 1.f;
        o[c] = eluv + A_PARA * __cosf(hv + PHI);
    }
    float* op = out + (size_t)row * FOUT + col0;
    *(float4*)op = make_float4(o[0], o[1], o[2], o[3]);
    *(float4*)(op + 4) = make_float4(o[4], o[5], o[6], o[7]);
}

extern "C" void kernel_launch(void* const* d_in, const int* in_sizes, int n_in,
                              void* d_out, int out_size, void* d_ws, size_t ws_size,
                              hipStream_t stream) {
    const float* h   = (const float*)d_in[0];
    const int*   adj = (const int*)d_in[1];
    const float* W   = (const float*)d_in[2];
    const float* a   = (const float*)d_in[3];
    float* out = (float*)d_out;

    char* ws = (char*)d_ws;
    unsigned short* whbt = (unsigned short*)ws;                 // 2 MB bf16 Wh^T
    size_t off = (size_t)N * FOUT * 2;
    unsigned short* Wt = (unsigned short*)(ws + off); off += (size_t)FOUT * FIN * 2;  // 128 KB
    float* s  = (float*)(ws + off); off += (size_t)N * 4;
    float* tt = (float*)(ws + off); off += (size_t)N * 4;
    unsigned* Tkey = (unsigned*)(ws + off); off += 256;
    float* denb = (float*)(ws + off); off += (size_t)N * 4;
    const size_t slice_bytes = (size_t)N * FOUT * 2;            // bf16 slices, 2 MB each
    const bool fast = ws_size >= off + 8 * slice_bytes;
    unsigned short* numb = fast ? (unsigned short*)(ws + off) : nullptr;

    if (!fast) hipMemsetAsync(out, 0, (size_t)N * FOUT * 4, stream);

    k0_wt<<<64, 256, 0, stream>>>(W, Wt, Tkey, denb);
    k1_gemm<<<N / 16, 256, 0, stream>>>(h, Wt, a, whbt, s, tt, Tkey);
    k3_attn<<<512, 512, 0, stream>>>(adj, whbt, s, tt, Tkey, numb, out, denb, fast ? 1 : 0);
    k4_epi<<<N / 16, 256, 0, stream>>>(numb, out, denb, out, fast ? 1 : 0);
}

// Round 6
// 97.196 us; speedup vs baseline: 1.1618x; 1.1618x over previous
//
#include <hip/hip_runtime.h>
#include <hip/hip_bf16.h>
#include <math.h>

typedef short short8 __attribute__((ext_vector_type(8)));
typedef float f32x4 __attribute__((ext_vector_type(4)));

static constexpr int N = 8192;
static constexpr int FIN = 512;
static constexpr int FOUT = 128;
static constexpr float PHI = 3.1415926f * 0.3f;
static constexpr float A_PARA = 0.5f;
static constexpr float EPS_BALL = 4e-3f;
static constexpr float L2E = 1.4426950408889634f;   // log2(e)

__device__ __forceinline__ unsigned short f2b(float f) {
    union { float f; unsigned u; } v; v.f = f;
    unsigned r = v.u + 0x7fffu + ((v.u >> 16) & 1u);
    return (unsigned short)(r >> 16);
}

// monotone f32 -> u32 key for atomicMax-based float max
__device__ __forceinline__ unsigned f2key(float x) {
    unsigned b = __float_as_uint(x);
    return (b & 0x80000000u) ? ~b : (b | 0x80000000u);
}
__device__ __forceinline__ float key2f(unsigned k) {
    unsigned b = (k & 0x80000000u) ? (k ^ 0x80000000u) : ~k;
    return __uint_as_float(b);
}

__device__ __forceinline__ short8 cvt8(float4 x0, float4 x1) {
    short8 r;
    r[0] = (short)f2b(x0.x); r[1] = (short)f2b(x0.y);
    r[2] = (short)f2b(x0.z); r[3] = (short)f2b(x0.w);
    r[4] = (short)f2b(x1.x); r[5] = (short)f2b(x1.y);
    r[6] = (short)f2b(x1.z); r[7] = (short)f2b(x1.w);
    return r;
}

// w = exp2( lrelu(s'+t') - m' ) masked by adj; everything pre-scaled by log2e.
__device__ __forceinline__ void cw(float* w, const int4 a, const float4 tv,
                                   float sA, float mA) {
    float z;
    z = sA + tv.x; w[0] = a.x > 0 ? __builtin_amdgcn_exp2f(fmaxf(z, 0.2f * z) - mA) : 0.f;
    z = sA + tv.y; w[1] = a.y > 0 ? __builtin_amdgcn_exp2f(fmaxf(z, 0.2f * z) - mA) : 0.f;
    z = sA + tv.z; w[2] = a.z > 0 ? __builtin_amdgcn_exp2f(fmaxf(z, 0.2f * z) - mA) : 0.f;
    z = sA + tv.w; w[3] = a.w > 0 ? __builtin_amdgcn_exp2f(fmaxf(z, 0.2f * z) - mA) : 0.f;
}

// Kernel 0: W f32[512][128] -> Wt bf16[128][512]; block 0 also zeroes Tkey + denb.
__global__ __launch_bounds__(256) void k0_wt(const float* __restrict__ W,
                                             unsigned short* __restrict__ Wt,
                                             unsigned* __restrict__ Tkey,
                                             float* __restrict__ denb) {
    __shared__ float sh[32][33];
    const int t = threadIdx.x;
    const int k0 = (blockIdx.x >> 2) * 32, c0 = (blockIdx.x & 3) * 32;
    {
        int r = t >> 3, c4 = (t & 7) * 4;
        float4 v = *(const float4*)(W + (size_t)(k0 + r) * FOUT + c0 + c4);
        sh[r][c4] = v.x; sh[r][c4 + 1] = v.y; sh[r][c4 + 2] = v.z; sh[r][c4 + 3] = v.w;
    }
    __syncthreads();
    int cc = t >> 3, k4 = (t & 7) * 4;
    ushort4 o;
    o.x = f2b(sh[k4][cc]); o.y = f2b(sh[k4 + 1][cc]);
    o.z = f2b(sh[k4 + 2][cc]); o.w = f2b(sh[k4 + 3][cc]);
    *(ushort4*)(Wt + (size_t)(c0 + cc) * FIN + k0 + k4) = o;
    if (blockIdx.x == 0) {
        if (t == 0) Tkey[0] = 0u;
        for (int i = t; i < N; i += 256) denb[i] = 0.f;
    }
}

// Kernel 1 (round-4 proven version): Wh = h @ W via bf16 MFMA (f32 accum).
// BM=32, grid 256, 4 waves (wr row-half, wc col-half), h tile double-buffered.
__global__ __launch_bounds__(256) void k1_gemm(
    const float* __restrict__ h, const unsigned short* __restrict__ Wt,
    const float* __restrict__ a, unsigned short* __restrict__ whbt,
    float* __restrict__ s_out, float* __restrict__ t_out,
    unsigned* __restrict__ Tkey)
{
    __shared__ unsigned short hsb[2][32][72];
    __shared__ float sred[32][2], tred[32][2];
    const int t = threadIdx.x, lane = t & 63, wave = t >> 6;
    const int i0 = blockIdx.x * 32;
    const int wr = wave & 1, wc = wave >> 1;
    const int arow = lane & 15, g = lane >> 4;
    const int sr = t >> 3, sc = (t & 7) * 8;
    const float* hp = h + (size_t)(i0 + sr) * FIN + sc;

    float4 x0 = *(const float4*)hp, x1 = *(const float4*)(hp + 4);
    *(short8*)&hsb[0][sr][sc] = cvt8(x0, x1);
    __syncthreads();

    f32x4 acc[4];
    const f32x4 zz = {0.f, 0.f, 0.f, 0.f};
    #pragma unroll
    for (int cf = 0; cf < 4; ++cf) acc[cf] = zz;

    #pragma unroll 1
    for (int kt = 0; kt < 8; ++kt) {
        const int cur = kt & 1;
        float4 y0, y1;
        if (kt < 7) {
            y0 = *(const float4*)(hp + (kt + 1) * 64);
            y1 = *(const float4*)(hp + (kt + 1) * 64 + 4);
        }
        #pragma unroll
        for (int js = 0; js < 64; js += 32) {
            short8 af = *(const short8*)&hsb[cur][wr * 16 + arow][js + g * 8];
            #pragma unroll
            for (int cf = 0; cf < 4; ++cf) {
                const unsigned short* bp =
                    Wt + (size_t)(wc * 64 + cf * 16 + arow) * FIN + kt * 64 + js + g * 8;
                short8 bf = *(const short8*)bp;
                acc[cf] = __builtin_amdgcn_mfma_f32_16x16x32_bf16(af, bf, acc[cf], 0, 0, 0);
            }
        }
        if (kt < 7) {
            *(short8*)&hsb[cur ^ 1][sr][sc] = cvt8(y0, y1);
            __syncthreads();
        }
    }

    float a1v[4], a2v[4];
    #pragma unroll
    for (int cf = 0; cf < 4; ++cf) {
        int col = wc * 64 + cf * 16 + arow;
        a1v[cf] = a[col]; a2v[cf] = a[FOUT + col];
    }
    #pragma unroll
    for (int cf = 0; cf < 4; ++cf) {
        int col = wc * 64 + cf * 16 + arow;
        ushort4 o;
        o.x = f2b(acc[cf][0]); o.y = f2b(acc[cf][1]);
        o.z = f2b(acc[cf][2]); o.w = f2b(acc[cf][3]);
        *(ushort4*)(whbt + (size_t)col * N + i0 + wr * 16 + g * 4) = o;
    }
    #pragma unroll
    for (int q = 0; q < 4; ++q) {
        float sp = acc[0][q]*a1v[0] + acc[1][q]*a1v[1] + acc[2][q]*a1v[2] + acc[3][q]*a1v[3];
        float tp = acc[0][q]*a2v[0] + acc[1][q]*a2v[1] + acc[2][q]*a2v[2] + acc[3][q]*a2v[3];
        #pragma unroll
        for (int m = 1; m < 16; m <<= 1) {
            sp += __shfl_xor(sp, m, 16);
            tp += __shfl_xor(tp, m, 16);
        }
        if (arow == 0) {
            sred[wr * 16 + g * 4 + q][wc] = sp;
            tred[wr * 16 + g * 4 + q][wc] = tp;
        }
    }
    __syncthreads();
    if (t < 32) {
        float sp = (sred[t][0] + sred[t][1]) * L2E;
        float tp = (tred[t][0] + tred[t][1]) * L2E;
        s_out[i0 + t] = sp;
        t_out[i0 + t] = tp;
        float m = tp;
        #pragma unroll
        for (int d = 1; d < 32; d <<= 1) m = fmaxf(m, __shfl_xor(m, d, 32));
        if (t == 0) atomicMax(Tkey, f2key(m));
    }
}

// Kernel 3: fused masked-softmax attention + PV (bf16 MFMA).
// Round-4 structure, ONE change: per-iter load issue order is whbt-next FIRST,
// adj-next LAST (1-deep). The ds_write then waits with a counted vmcnt(4) and
// the adj loads stay in flight across the barrier into next iter's phase A.
__global__ __launch_bounds__(512, 4) void k3_attn(
    const int* __restrict__ adj, const unsigned short* __restrict__ whbt,
    const float* __restrict__ s_in, const float* __restrict__ t_in,
    const unsigned* __restrict__ Tkey,
    unsigned short* __restrict__ num_bf, float* __restrict__ num_f32,
    float* __restrict__ den_out, int slice_mode)
{
    __shared__ unsigned short bt[2][128][72];
    __shared__ float tl[1024];
    const int t = threadIdx.x, lane = t & 63, wave = t >> 6;
    const int jc = blockIdx.x & 7, it = blockIdx.x >> 3;
    const int i0 = it * 128, jbase = jc * 1024;

    tl[t] = t_in[jbase + t];
    tl[t + 512] = t_in[jbase + t + 512];

    const int arow = lane & 15, g = lane >> 4;
    const int grow = i0 + wave * 16 + arow;
    const float sA = s_in[grow];
    const float Tv = key2f(Tkey[0]);
    const float zT = sA + Tv;
    const float mA = fmaxf(zT, 0.2f * zT);
    const int* adjrow = adj + (size_t)grow * N;
    const int srow = t >> 2, scol = (t & 3) * 16;
    const unsigned short* sbase = whbt + (size_t)srow * N + jbase + scol;

    f32x4 acc[8];
    const f32x4 zz = {0.f, 0.f, 0.f, 0.f};
    #pragma unroll
    for (int c = 0; c < 8; ++c) acc[c] = zz;
    float den = 0.f;

    // prologue: stage bt tile 0, prefetch adj for jt=0
    short8 sr0 = *(const short8*)sbase;
    short8 sr1 = *(const short8*)(sbase + 8);
    int4 av0 = *(const int4*)(adjrow + jbase + g * 8);
    int4 av1 = *(const int4*)(adjrow + jbase + g * 8 + 4);
    int4 av2 = *(const int4*)(adjrow + jbase + 32 + g * 8);
    int4 av3 = *(const int4*)(adjrow + jbase + 32 + g * 8 + 4);
    *(short8*)&bt[0][srow][scol]     = sr0;
    *(short8*)&bt[0][srow][scol + 8] = sr1;
    __syncthreads();

    #pragma unroll 1
    for (int jt = 0; jt < 16; ++jt) {
        const int cur = jt & 1, jl = jt * 64;
        // whbt-next FIRST (oldest outstanding -> counted vmcnt at the ds_write)
        short8 n0, n1;
        if (jt < 15) {
            const unsigned short* p = sbase + (jt + 1) * 64;
            n0 = *(const short8*)p;
            n1 = *(const short8*)(p + 8);
        }
        // adj for jt+1 LAST (stays in flight across the barrier)
        int4 an0, an1, an2, an3;
        if (jt < 15) {
            const int* ap = adjrow + jbase + jl + 64;
            an0 = *(const int4*)(ap + g * 8);
            an1 = *(const int4*)(ap + g * 8 + 4);
            an2 = *(const int4*)(ap + 32 + g * 8);
            an3 = *(const int4*)(ap + 32 + g * 8 + 4);
        }
        // t' from LDS (lgkm only)
        float4 ta = *(const float4*)&tl[jl + g * 8];
        float4 tb = *(const float4*)&tl[jl + g * 8 + 4];
        float4 tc = *(const float4*)&tl[jl + 32 + g * 8];
        float4 td = *(const float4*)&tl[jl + 32 + g * 8 + 4];
        // phase A: 16 w's straight into A-fragments (adj already in regs)
        float w[16];
        cw(&w[0],  av0, ta, sA, mA);
        cw(&w[4],  av1, tb, sA, mA);
        cw(&w[8],  av2, tc, sA, mA);
        cw(&w[12], av3, td, sA, mA);
        #pragma unroll
        for (int e = 0; e < 16; ++e) den += w[e];
        short8 af0, af1;
        #pragma unroll
        for (int e = 0; e < 8; ++e) {
            af0[e] = (short)f2b(w[e]);
            af1[e] = (short)f2b(w[8 + e]);
        }
        // phase B: 16 MFMA, B from LDS
        #pragma unroll
        for (int c = 0; c < 8; ++c) {
            short8 bf = *(const short8*)&bt[cur][c * 16 + arow][g * 8];
            acc[c] = __builtin_amdgcn_mfma_f32_16x16x32_bf16(af0, bf, acc[c], 0, 0, 0);
        }
        #pragma unroll
        for (int c = 0; c < 8; ++c) {
            short8 bf = *(const short8*)&bt[cur][c * 16 + arow][32 + g * 8];
            acc[c] = __builtin_amdgcn_mfma_f32_16x16x32_bf16(af1, bf, acc[c], 0, 0, 0);
        }
        // stage next tile (counted vmcnt drains only n0/n1); shift adj regs
        if (jt < 15) {
            *(short8*)&bt[cur ^ 1][srow][scol]     = n0;
            *(short8*)&bt[cur ^ 1][srow][scol + 8] = n1;
            av0 = an0; av1 = an1; av2 = an2; av3 = an3;
            __syncthreads();
        }
    }

    // den: sum the 4 g-copies per row
    den += __shfl_xor(den, 16, 64);
    den += __shfl_xor(den, 32, 64);
    if (g == 0) atomicAdd(&den_out[grow], den);

    // num partials
    const int orow0 = i0 + wave * 16;
    if (slice_mode) {
        unsigned short* dst = num_bf + (size_t)jc * ((size_t)N * FOUT);
        #pragma unroll
        for (int c = 0; c < 8; ++c)
            #pragma unroll
            for (int q = 0; q < 4; ++q)
                dst[(size_t)(orow0 + g * 4 + q) * FOUT + c * 16 + arow] = f2b(acc[c][q]);
    } else {
        #pragma unroll
        for (int c = 0; c < 8; ++c)
            #pragma unroll
            for (int q = 0; q < 4; ++q)
                atomicAdd(&num_f32[(size_t)(orow0 + g * 4 + q) * FOUT + c * 16 + arow], acc[c][q]);
    }
}

// Kernel 4: reduce j-chunk partials, normalize, project, logmap0, elu + a*cos.
// Thread owns 8 CONTIGUOUS cols of one row -> short8 slice loads, float4 stores.
__global__ __launch_bounds__(256) void k4_epi(
    const unsigned short* __restrict__ numb, const float* __restrict__ numf,
    const float* __restrict__ den, float* __restrict__ out, int bfmode)
{
    const int row = blockIdx.x * 16 + (threadIdx.x >> 4);
    const int col0 = (threadIdx.x & 15) * 8;
    const float inv = 1.0f / den[row];
    float v[8] = {};
    if (bfmode) {
        #pragma unroll 1
        for (int s5 = 0; s5 < 8; ++s5) {
            short8 b = *(const short8*)(numb + (size_t)s5 * N * FOUT + (size_t)row * FOUT + col0);
            #pragma unroll
            for (int c = 0; c < 8; ++c)
                v[c] += __uint_as_float(((unsigned)(unsigned short)b[c]) << 16);
        }
    } else {
        #pragma unroll
        for (int c = 0; c < 8; ++c) v[c] = numf[(size_t)row * FOUT + col0 + c];
    }
    float ss = 0.f;
    #pragma unroll
    for (int c = 0; c < 8; ++c) { v[c] *= inv; ss += v[c] * v[c]; }
    #pragma unroll
    for (int m = 1; m < 16; m <<= 1) ss += __shfl_xor(ss, m, 16);
    float nrm = sqrtf(ss);
    const float maxn = 1.0f - EPS_BALL;
    float scale1 = nrm > maxn ? maxn / nrm : 1.0f;
    float pn = fminf(nrm, maxn);
    float fac;
    if (pn < 1e-6f) fac = scale1;   // artanh(x)/x -> 1
    else fac = scale1 * (0.5f * __logf((1.f + pn) / (1.f - pn))) / pn;
    float o[8];
    #pragma unroll
    for (int c = 0; c < 8; ++c) {
        float hv = v[c] * fac;
        float eluv = hv > 0.f ? hv : __expf(hv) - 1.f;
        o[c] = eluv + A_PARA * __cosf(hv + PHI);
    }
    float* op = out + (size_t)row * FOUT + col0;
    *(float4*)op = make_float4(o[0], o[1], o[2], o[3]);
    *(float4*)(op + 4) = make_float4(o[4], o[5], o[6], o[7]);
}

extern "C" void kernel_launch(void* const* d_in, const int* in_sizes, int n_in,
                              void* d_out, int out_size, void* d_ws, size_t ws_size,
                              hipStream_t stream) {
    const float* h   = (const float*)d_in[0];
    const int*   adj = (const int*)d_in[1];
    const float* W   = (const float*)d_in[2];
    const float* a   = (const float*)d_in[3];
    float* out = (float*)d_out;

    char* ws = (char*)d_ws;
    unsigned short* whbt = (unsigned short*)ws;                 // 2 MB bf16 Wh^T
    size_t off = (size_t)N * FOUT * 2;
    unsigned short* Wt = (unsigned short*)(ws + off); off += (size_t)FOUT * FIN * 2;  // 128 KB
    float* s  = (float*)(ws + off); off += (size_t)N * 4;
    float* tt = (float*)(ws + off); off += (size_t)N * 4;
    unsigned* Tkey = (unsigned*)(ws + off); off += 256;
    float* denb = (float*)(ws + off); off += (size_t)N * 4;
    const size_t slice_bytes = (size_t)N * FOUT * 2;            // bf16 slices, 2 MB each
    const bool fast = ws_size >= off + 8 * slice_bytes;
    unsigned short* numb = fast ? (unsigned short*)(ws + off) : nullptr;

    if (!fast) hipMemsetAsync(out, 0, (size_t)N * FOUT * 4, stream);

    k0_wt<<<64, 256, 0, stream>>>(W, Wt, Tkey, denb);
    k1_gemm<<<N / 32, 256, 0, stream>>>(h, Wt, a, whbt, s, tt, Tkey);
    k3_attn<<<512, 512, 0, stream>>>(adj, whbt, s, tt, Tkey, numb, out, denb, fast ? 1 : 0);
    k4_epi<<<N / 16, 256, 0, stream>>>(numb, out, denb, out, fast ? 1 : 0);
}